// Round 6
// baseline (41.222 us; speedup 1.0000x reference)
//
#include <hip/hip_runtime.h>
#include <hip/hip_fp16.h>

#define NUF 100000
#define NIF 100000
#define DIM 64
#define LNZ 32
#define NB 16384
#define NI 16384
#define OUTW 66   // D + 2

// ---------------- Kernel A: f32 tables -> fp16 rows in ws ----------------
// 2048 blocks, XCD-side-sharded to match the gather: (blockIdx&7)<4 -> user
// table, else item table. Each side: 262144 threads grid-stride over 800000
// float8 chunks. fp16 row = 128B = one L2 line.
__global__ __launch_bounds__(256) void cvt_kernel(
    const float* __restrict__ ue, const float* __restrict__ ie,
    const float* __restrict__ h2, unsigned short* __restrict__ wsh,
    float* __restrict__ out)
{
    // h2 passthrough
    if (blockIdx.x == 0 && threadIdx.x < DIM) {
        out[(size_t)(NB + NI) * OUTW + threadIdx.x] = h2[threadIdx.x];
    }

    const int xcd      = blockIdx.x & 7;
    const bool is_user = (xcd < 4);
    const int sideblk  = (blockIdx.x >> 3) * 4 + (xcd & 3);      // 0..1023
    const int tsid     = sideblk * 256 + threadIdx.x;            // 0..262143

    const float* src0 = is_user ? ue : ie;
    unsigned short* dst0 = wsh + (is_user ? 0 : (size_t)NUF * DIM);

    const int nOct = NUF * DIM / 8;                              // 800000
    for (int o = tsid; o < nOct; o += 262144) {
        const float* s = src0 + (size_t)o * 8;
        float a0 = __builtin_nontemporal_load(s + 0);
        float a1 = __builtin_nontemporal_load(s + 1);
        float a2 = __builtin_nontemporal_load(s + 2);
        float a3 = __builtin_nontemporal_load(s + 3);
        float a4 = __builtin_nontemporal_load(s + 4);
        float a5 = __builtin_nontemporal_load(s + 5);
        float a6 = __builtin_nontemporal_load(s + 6);
        float a7 = __builtin_nontemporal_load(s + 7);
        uint4 p;
        p.x = (unsigned)__half_as_ushort(__float2half_rn(a0))
            | ((unsigned)__half_as_ushort(__float2half_rn(a1)) << 16);
        p.y = (unsigned)__half_as_ushort(__float2half_rn(a2))
            | ((unsigned)__half_as_ushort(__float2half_rn(a3)) << 16);
        p.z = (unsigned)__half_as_ushort(__float2half_rn(a4))
            | ((unsigned)__half_as_ushort(__float2half_rn(a5)) << 16);
        p.w = (unsigned)__half_as_ushort(__float2half_rn(a6))
            | ((unsigned)__half_as_ushort(__float2half_rn(a7)) << 16);
        *reinterpret_cast<uint4*>(dst0 + (size_t)o * 8) = p;     // keep in L2
    }
}

// ---------------- Kernel B: gather from fp16 rows ------------------------
// 8 rows per wave: 8-lane group per row, lane owns dims 8t..8t+7 (16B=uint4).
// One 128B L2 line per row-gather. XCD side-shard matches cvt.
__global__ __launch_bounds__(256) void ensfm_f16_kernel(
    const unsigned short* __restrict__ wsh,
    const float* __restrict__ w_user,
    const float* __restrict__ w_item,
    const float* __restrict__ gbias,
    const float* __restrict__ h1,
    const int*   __restrict__ u_idx,
    const int*   __restrict__ i_idx,
    float* __restrict__ out)
{
    const int lane = threadIdx.x & 63;
    const int wib  = threadIdx.x >> 6;          // wave in block (0..3)
    const int t    = lane & 7;                  // lane in row-group
    const int g    = lane >> 3;                 // row-group in wave (0..7)

    const int xcd      = blockIdx.x & 7;
    const bool is_user = (xcd < 4);
    const int sideblk  = (blockIdx.x >> 3) * 4 + (xcd & 3);      // 0..511
    const int r        = sideblk * 32 + wib * 8 + g;             // 0..16383

    const unsigned short* emb = is_user ? wsh : (wsh + (size_t)NUF * DIM);
    const float* wtab = is_user ? w_user : w_item;
    const int*   idxp = is_user ? u_idx  : i_idx;

    // each lane loads 4 of its row's 32 indices
    const int* ib = idxp + (size_t)r * LNZ + 4 * t;
    int4 m;
    m.x = __builtin_nontemporal_load(ib + 0);
    m.y = __builtin_nontemporal_load(ib + 1);
    m.z = __builtin_nontemporal_load(ib + 2);
    m.w = __builtin_nontemporal_load(ib + 3);

    // w gather + 8-lane group sum
    float wsum = wtab[m.x] + wtab[m.y] + wtab[m.z] + wtab[m.w];
    #pragma unroll
    for (int s = 1; s < 8; s <<= 1) wsum += __shfl_xor(wsum, s, 64);

    float su[8] = {0.f,0.f,0.f,0.f,0.f,0.f,0.f,0.f};
    float ss[8] = {0.f,0.f,0.f,0.f,0.f,0.f,0.f,0.f};
    const int rbase = lane & 56;                // g*8

    #pragma unroll
    for (int l = 0; l < LNZ; ++l) {
        const int c   = l & 3;
        const int src = rbase | (l >> 2);
        const int idx = __shfl(c == 0 ? m.x : c == 1 ? m.y : c == 2 ? m.z : m.w,
                               src, 64);
        const uint4 ev = *reinterpret_cast<const uint4*>(
            emb + (size_t)idx * DIM + 8 * t);
        const float2 f0 = __half22float2(*reinterpret_cast<const __half2*>(&ev.x));
        const float2 f1 = __half22float2(*reinterpret_cast<const __half2*>(&ev.y));
        const float2 f2 = __half22float2(*reinterpret_cast<const __half2*>(&ev.z));
        const float2 f3 = __half22float2(*reinterpret_cast<const __half2*>(&ev.w));
        su[0] += f0.x; ss[0] = fmaf(f0.x, f0.x, ss[0]);
        su[1] += f0.y; ss[1] = fmaf(f0.y, f0.y, ss[1]);
        su[2] += f1.x; ss[2] = fmaf(f1.x, f1.x, ss[2]);
        su[3] += f1.y; ss[3] = fmaf(f1.y, f1.y, ss[3]);
        su[4] += f2.x; ss[4] = fmaf(f2.x, f2.x, ss[4]);
        su[5] += f2.y; ss[5] = fmaf(f2.y, f2.y, ss[5]);
        su[6] += f3.x; ss[6] = fmaf(f3.x, f3.x, ss[6]);
        su[7] += f3.y; ss[7] = fmaf(f3.y, f3.y, ss[7]);
    }

    // dot(bi, h1) over this lane's 8 dims, then 8-lane reduce
    float dot = 0.f;
    #pragma unroll
    for (int k = 0; k < 8; ++k) {
        dot = fmaf(0.5f * (su[k] * su[k] - ss[k]), h1[8 * t + k], dot);
    }
    #pragma unroll
    for (int s = 1; s < 8; s <<= 1) dot += __shfl_xor(dot, s, 64);

    const float scal = dot + wsum + (is_user ? gbias[0] : 0.0f);

    const int orow_i = is_user ? r : (NB + r);
    float* orow = out + (size_t)orow_i * OUTW + 8 * t;
    #pragma unroll
    for (int k = 0; k < 8; ++k) __builtin_nontemporal_store(su[k], orow + k);
    if (t == 0) {
        float* otail = out + (size_t)orow_i * OUTW + DIM;
        if (is_user) {
            __builtin_nontemporal_store(scal, otail);
            __builtin_nontemporal_store(1.0f, otail + 1);
        } else {
            __builtin_nontemporal_store(1.0f, otail);
            __builtin_nontemporal_store(scal, otail + 1);
        }
    }
}

// ---------------- Fallback: f32 gather (if ws too small) -----------------
__global__ __launch_bounds__(256) void ensfm_f32_kernel(
    const float* __restrict__ ue_emb, const float* __restrict__ ie_emb,
    const float* __restrict__ w_user, const float* __restrict__ w_item,
    const float* __restrict__ gbias,  const float* __restrict__ h1,
    const float* __restrict__ h2,
    const int* __restrict__ u_idx, const int* __restrict__ i_idx,
    float* __restrict__ out)
{
    const int lane = threadIdx.x & 63;
    const int wib  = threadIdx.x >> 6;
    const int g    = lane >> 4;
    const int t    = lane & 15;
    if (blockIdx.x == 0 && threadIdx.x < DIM)
        out[(size_t)(NB + NI) * OUTW + threadIdx.x] = h2[threadIdx.x];
    const int xcd      = blockIdx.x & 7;
    const bool is_user = (xcd < 4);
    const int sideblk  = (blockIdx.x >> 3) * 4 + (xcd & 3);
    const int r        = sideblk * 16 + wib * 4 + g;
    const float* emb  = is_user ? ue_emb : ie_emb;
    const float* wtab = is_user ? w_user : w_item;
    const int*   idxp = is_user ? u_idx  : i_idx;
    const int2 myidx = *reinterpret_cast<const int2*>(idxp + (size_t)r * LNZ + 2 * t);
    float wsum = wtab[myidx.x] + wtab[myidx.y];
    #pragma unroll
    for (int s = 1; s < 16; s <<= 1) wsum += __shfl_xor(wsum, s, 64);
    float4 su = {0.f,0.f,0.f,0.f}, ss = {0.f,0.f,0.f,0.f};
    const int gbase = lane & 48;
    #pragma unroll
    for (int l = 0; l < LNZ; ++l) {
        const int idx = __shfl((l & 1) ? myidx.y : myidx.x, gbase | (l >> 1), 64);
        const float4 e = *reinterpret_cast<const float4*>(emb + (size_t)idx * DIM + 4 * t);
        su.x += e.x; su.y += e.y; su.z += e.z; su.w += e.w;
        ss.x = fmaf(e.x,e.x,ss.x); ss.y = fmaf(e.y,e.y,ss.y);
        ss.z = fmaf(e.z,e.z,ss.z); ss.w = fmaf(e.w,e.w,ss.w);
    }
    const float4 h1v = *reinterpret_cast<const float4*>(h1 + 4 * t);
    float dot = 0.5f*(su.x*su.x-ss.x)*h1v.x + 0.5f*(su.y*su.y-ss.y)*h1v.y
              + 0.5f*(su.z*su.z-ss.z)*h1v.z + 0.5f*(su.w*su.w-ss.w)*h1v.w;
    #pragma unroll
    for (int s = 1; s < 16; s <<= 1) dot += __shfl_xor(dot, s, 64);
    const float scal = dot + wsum + (is_user ? gbias[0] : 0.0f);
    const int orow_i = is_user ? r : (NB + r);
    float* orow = out + (size_t)orow_i * OUTW;
    orow[4*t] = su.x; orow[4*t+1] = su.y; orow[4*t+2] = su.z; orow[4*t+3] = su.w;
    if (t == 0) {
        if (is_user) { orow[DIM] = scal; orow[DIM+1] = 1.0f; }
        else         { orow[DIM] = 1.0f; orow[DIM+1] = scal; }
    }
}

extern "C" void kernel_launch(void* const* d_in, const int* in_sizes, int n_in,
                              void* d_out, int out_size, void* d_ws, size_t ws_size,
                              hipStream_t stream) {
    const float* ue_emb = (const float*)d_in[0];
    const float* ie_emb = (const float*)d_in[1];
    const float* w_user = (const float*)d_in[2];
    const float* w_item = (const float*)d_in[3];
    const float* gbias  = (const float*)d_in[4];
    const float* h1     = (const float*)d_in[5];
    const float* h2     = (const float*)d_in[6];
    const int*   u_idx  = (const int*)d_in[7];
    const int*   i_idx  = (const int*)d_in[8];
    float* out = (float*)d_out;

    const size_t need = (size_t)(NUF + NIF) * DIM * 2;   // 25.6 MB fp16 tables

    if (ws_size >= need && d_ws != nullptr) {
        unsigned short* wsh = (unsigned short*)d_ws;
        cvt_kernel<<<2048, 256, 0, stream>>>(ue_emb, ie_emb, h2, wsh, out);
        ensfm_f16_kernel<<<1024, 256, 0, stream>>>(
            wsh, w_user, w_item, gbias, h1, u_idx, i_idx, out);
    } else {
        ensfm_f32_kernel<<<2048, 256, 0, stream>>>(
            ue_emb, ie_emb, w_user, w_item, gbias, h1, h2, u_idx, i_idx, out);
    }
}

// Round 7
// 39.767 us; speedup vs baseline: 1.0366x; 1.0366x over previous
//
#include <hip/hip_runtime.h>

#define NUF 100000
#define NIF 100000
#define DIM 64
#define LNZ 32
#define NB 16384
#define NI 16384
#define OUTW 66   // D + 2

// 4 rows per wave: 16-lane group per row, each lane owns 4 dims (float4).
// XCD-sharded: blocks with (blockIdx&7)<4 process users, others items, so each
// XCD's L2 only sees ONE 25.6 MB embedding table instead of both (51 MB).
// Measured: 39.8 us, FETCH 117.6 MB @ ~3.0 TB/s random-line path (MSHR-bound),
// VALUBusy ~10%. This is ~97% of the arithmetic floor for the one-pass design.
__global__ __launch_bounds__(256) void ensfm_kernel(
    const float* __restrict__ ue_emb,   // [NUF, 64]
    const float* __restrict__ ie_emb,   // [NIF, 64]
    const float* __restrict__ w_user,   // [NUF]
    const float* __restrict__ w_item,   // [NIF]
    const float* __restrict__ gbias,    // [1]
    const float* __restrict__ h1,       // [64]
    const float* __restrict__ h2,       // [64]
    const int*   __restrict__ u_idx,    // [NB, 32]
    const int*   __restrict__ i_idx,    // [NI, 32]
    float* __restrict__ out)            // P [NB,66] | Q [NI,66] | h2 [64]
{
    const int lane = threadIdx.x & 63;
    const int wib  = threadIdx.x >> 6;          // wave in block (0..3)
    const int g    = lane >> 4;                 // row-group in wave (0..3)
    const int t    = lane & 15;                 // lane in group; owns dims 4t..4t+3

    // h2 passthrough (block 0 only)
    if (blockIdx.x == 0 && threadIdx.x < DIM) {
        out[(size_t)(NB + NI) * OUTW + threadIdx.x] = h2[threadIdx.x];
    }

    // XCD shard: round-robin dispatch puts block b on XCD b&7.
    const int xcd      = blockIdx.x & 7;
    const bool is_user = (xcd < 4);
    const int sideblk  = (blockIdx.x >> 3) * 4 + (xcd & 3);   // 0..1023
    const int r        = sideblk * 16 + wib * 4 + g;          // 0..16383

    const float* emb  = is_user ? ue_emb : ie_emb;
    const float* wtab = is_user ? w_user : w_item;
    const int*   idxp = is_user ? u_idx  : i_idx;

    // each lane loads 2 of its row's 32 indices (streaming -> nontemporal)
    const int* ibase = idxp + (size_t)r * LNZ + 2 * t;
    int2 myidx;
    myidx.x = __builtin_nontemporal_load(ibase);
    myidx.y = __builtin_nontemporal_load(ibase + 1);

    // w gather + 16-lane group sum
    float wsum = wtab[myidx.x] + wtab[myidx.y];
    #pragma unroll
    for (int m = 1; m < 16; m <<= 1) wsum += __shfl_xor(wsum, m, 64);

    // gather-accumulate over 32 features; idx for feature l lives in
    // lane (groupbase | l>>1), component l&1
    float4 su = {0.f, 0.f, 0.f, 0.f};
    float4 ss = {0.f, 0.f, 0.f, 0.f};
    const int gbase = lane & 48;
    #pragma unroll
    for (int l = 0; l < LNZ; ++l) {
        const int idx = __shfl((l & 1) ? myidx.y : myidx.x, gbase | (l >> 1), 64);
        const float4 e = *reinterpret_cast<const float4*>(emb + (size_t)idx * DIM + 4 * t);
        su.x += e.x; su.y += e.y; su.z += e.z; su.w += e.w;
        ss.x = fmaf(e.x, e.x, ss.x);
        ss.y = fmaf(e.y, e.y, ss.y);
        ss.z = fmaf(e.z, e.z, ss.z);
        ss.w = fmaf(e.w, e.w, ss.w);
    }

    // bi = 0.5*(su^2 - ss); scal = dot(bi, h1) + wsum (+ bias for users)
    const float4 h1v = *reinterpret_cast<const float4*>(h1 + 4 * t);
    float dot = 0.5f * (su.x * su.x - ss.x) * h1v.x
              + 0.5f * (su.y * su.y - ss.y) * h1v.y
              + 0.5f * (su.z * su.z - ss.z) * h1v.z
              + 0.5f * (su.w * su.w - ss.w) * h1v.w;
    #pragma unroll
    for (int m = 1; m < 16; m <<= 1) dot += __shfl_xor(dot, m, 64);

    const float scal = dot + wsum + (is_user ? gbias[0] : 0.0f);

    // output row: users at r, items at NB + r (streaming -> nontemporal)
    const int orow_i = is_user ? r : (NB + r);
    float* orow = out + (size_t)orow_i * OUTW;
    __builtin_nontemporal_store(su.x, orow + 4 * t);
    __builtin_nontemporal_store(su.y, orow + 4 * t + 1);
    __builtin_nontemporal_store(su.z, orow + 4 * t + 2);
    __builtin_nontemporal_store(su.w, orow + 4 * t + 3);
    if (t == 0) {
        if (is_user) {
            __builtin_nontemporal_store(scal, orow + DIM);
            __builtin_nontemporal_store(1.0f, orow + DIM + 1);
        } else {
            __builtin_nontemporal_store(1.0f, orow + DIM);
            __builtin_nontemporal_store(scal, orow + DIM + 1);
        }
    }
}

extern "C" void kernel_launch(void* const* d_in, const int* in_sizes, int n_in,
                              void* d_out, int out_size, void* d_ws, size_t ws_size,
                              hipStream_t stream) {
    const float* ue_emb = (const float*)d_in[0];
    const float* ie_emb = (const float*)d_in[1];
    const float* w_user = (const float*)d_in[2];
    const float* w_item = (const float*)d_in[3];
    const float* gbias  = (const float*)d_in[4];
    const float* h1     = (const float*)d_in[5];
    const float* h2     = (const float*)d_in[6];
    const int*   u_idx  = (const int*)d_in[7];
    const int*   i_idx  = (const int*)d_in[8];
    float* out = (float*)d_out;

    const int blocks = (NB + NI) / 16;          // 2048 blocks x 256 threads
    ensfm_kernel<<<blocks, 256, 0, stream>>>(
        ue_emb, ie_emb, w_user, w_item, gbias, h1, h2, u_idx, i_idx, out);
}